// Round 1
// baseline (5828.456 us; speedup 1.0000x reference)
//
#include <hip/hip_runtime.h>
#include <hip/hip_fp16.h>

// Persistent clustered LSTM scan for MI355X.
// 4 clusters x 16 batch rows; 32 WGs/cluster; WG = 256 thr (4 waves).
// Wave w == gate w (i,f,g,o). Weights live in VGPRs (f16, 128 regs/lane).
// A = [x_t | h_t] f16 in LDS (32KB, rotate-by-8*row swizzle -> 2-way max).
// Per-cluster barrier: relaxed-agent atomic h exchange + release/acquire counter.

typedef _Float16 f16x8 __attribute__((ext_vector_type(8)));
typedef _Float16 f16x4 __attribute__((ext_vector_type(4)));
typedef float    f32x4 __attribute__((ext_vector_type(4)));

__device__ __forceinline__ float sigmoid_f(float v) {
    return 1.f / (1.f + __expf(-v));
}
__device__ __forceinline__ float tanh_f(float v) {
    v = fminf(15.f, fmaxf(-15.f, v));
    const float e = __expf(2.f * v);
    return (e - 1.f) / (e + 1.f);
}

__global__ __launch_bounds__(256, 1)
void lstm_persistent(const float* __restrict__ x,
                     const float* __restrict__ c0,
                     const float* __restrict__ h0,
                     const float* __restrict__ Wi,
                     const float* __restrict__ Wh,
                     const float* __restrict__ bias,
                     float* __restrict__ out,
                     unsigned* __restrict__ bar_base,
                     float* __restrict__ exch)  // 2 buffers x 64*512 f32
{
    const int bid  = blockIdx.x;
    // cluster = pairs of XCD-slots (blockIdx%8 heuristic); correctness-independent
    const int cl   = (bid & 7) >> 1;                     // 0..3
    const int wg   = ((bid >> 3) << 1) | (bid & 1);      // 0..31 within cluster
    const int tid  = threadIdx.x;
    const int w    = tid >> 6;                           // wave index == gate
    const int lane = tid & 63;
    const int q    = lane >> 4;                          // quad
    const int n16  = lane & 15;

    const int gb0  = cl * 16;                            // cluster's first batch row
    const int col0 = wg * 16;                            // this WG's first hidden col

    __shared__ _Float16 Alds[16 * 1024];                 // 32 KB: A = [x_t | h_t], rows=batch
    __shared__ float    glds[4][16][17];                 // gate exchange (padded)

    unsigned* bar = bar_base + cl * 32;                  // 128B-separated counters

    // ---------------- B preload into registers (persistent across all steps) ----
    // Wave w, lane: holds weight col cg = w*512 + col0 + n16, fragment layout
    // B[k][n]: lane n = lane&15, k = quad*8 + j  (per K-step of 32).
    f16x8 Breg[32];
    {
        const int cg = w * 512 + col0 + n16;
#pragma unroll
        for (int kk = 0; kk < 32; ++kk) {
            const int kbase = kk * 32 + q * 8;
            f16x8 v;
#pragma unroll
            for (int j = 0; j < 8; ++j) {
                const int k = kbase + j;                 // kk<16 -> Wi, else Wh (uniform)
                const float f = (k < 512) ? Wi[(size_t)k * 2048 + cg]
                                          : Wh[(size_t)(k - 512) * 2048 + cg];
                v[j] = (_Float16)f;
            }
            Breg[kk] = v;
        }
    }

    // ---------------- per-thread elementwise state: thread -> (batch eb, col ej) --
    const int eb = tid >> 4;                             // 0..15
    const int ej = tid & 15;                             // 0..15
    const float bi_i = bias[0 * 512 + col0 + ej];
    const float bi_f = bias[1 * 512 + col0 + ej];
    const float bi_g = bias[2 * 512 + col0 + ej];
    const float bi_o = bias[3 * 512 + col0 + ej];
    float cst = c0[(size_t)(gb0 + eb) * 512 + col0 + ej];

    // ---------------- prefetch x_0 into registers ------------------------------
    float4 xr[8];
#pragma unroll
    for (int cc = 0; cc < 8; ++cc) {
        const int chunk = tid + cc * 256;
        const int b  = chunk >> 7;
        const int k4 = chunk & 127;
        xr[cc] = *(const float4*)&x[((size_t)(gb0 + b) * 1024 + 0) * 512 + k4 * 4];
    }

    for (int t = 0; t < 1024; ++t) {
        // ---- wait for h_t to be fully published (all WGs arrived for step t-1) --
        if (t > 0) {
            if (tid == 0) {
                const unsigned target = 32u * (unsigned)t;
                int guard = 1 << 20;                      // deadlock safety valve
                while (__hip_atomic_load(bar, __ATOMIC_ACQUIRE,
                                         __HIP_MEMORY_SCOPE_AGENT) < target) {
                    __builtin_amdgcn_s_sleep(1);
                    if (--guard == 0) break;
                }
            }
            __syncthreads();
        }

        // ---- stage x_t (from prefetch regs) into A rows, f16, swizzled ---------
#pragma unroll
        for (int cc = 0; cc < 8; ++cc) {
            const int chunk = tid + cc * 256;
            const int b = chunk >> 7;
            const int k = (chunk & 127) * 4;
            f16x4 v;
            v[0] = (_Float16)xr[cc].x; v[1] = (_Float16)xr[cc].y;
            v[2] = (_Float16)xr[cc].z; v[3] = (_Float16)xr[cc].w;
            *(f16x4*)&Alds[b * 1024 + ((k + 8 * b) & 1023)] = v;
        }

        // ---- stage h_t into A rows ---------------------------------------------
        if (t == 0) {
#pragma unroll
            for (int cc = 0; cc < 4; ++cc) {
                const int chunk = tid + cc * 256;
                const int b  = chunk >> 6;
                const int k8 = chunk & 63;
                const float4 a0 = *(const float4*)&h0[(size_t)(gb0 + b) * 512 + k8 * 8];
                const float4 a1 = *(const float4*)&h0[(size_t)(gb0 + b) * 512 + k8 * 8 + 4];
                f16x8 v;
                v[0]=(_Float16)a0.x; v[1]=(_Float16)a0.y; v[2]=(_Float16)a0.z; v[3]=(_Float16)a0.w;
                v[4]=(_Float16)a1.x; v[5]=(_Float16)a1.y; v[6]=(_Float16)a1.z; v[7]=(_Float16)a1.w;
                *(f16x8*)&Alds[b * 1024 + ((512 + k8 * 8 + 8 * b) & 1023)] = v;
            }
        } else {
            const unsigned long long* src =
                (const unsigned long long*)(exch + (size_t)(t & 1) * (64 * 512));
#pragma unroll
            for (int cc = 0; cc < 4; ++cc) {
                const int chunk = tid + cc * 256;
                const int b  = chunk >> 6;
                const int k8 = chunk & 63;
                const int idx = ((gb0 + b) * 512 + k8 * 8) >> 1;   // ull = 2 f32
                union { unsigned long long u; float f[2]; } u0, u1, u2, u3;
                u0.u = __hip_atomic_load(&src[idx + 0], __ATOMIC_RELAXED, __HIP_MEMORY_SCOPE_AGENT);
                u1.u = __hip_atomic_load(&src[idx + 1], __ATOMIC_RELAXED, __HIP_MEMORY_SCOPE_AGENT);
                u2.u = __hip_atomic_load(&src[idx + 2], __ATOMIC_RELAXED, __HIP_MEMORY_SCOPE_AGENT);
                u3.u = __hip_atomic_load(&src[idx + 3], __ATOMIC_RELAXED, __HIP_MEMORY_SCOPE_AGENT);
                f16x8 v;
                v[0]=(_Float16)u0.f[0]; v[1]=(_Float16)u0.f[1];
                v[2]=(_Float16)u1.f[0]; v[3]=(_Float16)u1.f[1];
                v[4]=(_Float16)u2.f[0]; v[5]=(_Float16)u2.f[1];
                v[6]=(_Float16)u3.f[0]; v[7]=(_Float16)u3.f[1];
                *(f16x8*)&Alds[b * 1024 + ((512 + k8 * 8 + 8 * b) & 1023)] = v;
            }
        }
        __syncthreads();

        // ---- prefetch x_{t+1}: in flight across GEMM + barrier spin ------------
        if (t < 1023) {
#pragma unroll
            for (int cc = 0; cc < 8; ++cc) {
                const int chunk = tid + cc * 256;
                const int b  = chunk >> 7;
                const int k4 = chunk & 127;
                xr[cc] = *(const float4*)&x[((size_t)(gb0 + b) * 1024 + (t + 1)) * 512 + k4 * 4];
            }
        }

        // ---- GEMM: C[16b x 16col] = A[16 x 1024] * Breg, K chained, 2 accs -----
        f32x4 acc0 = {0.f, 0.f, 0.f, 0.f}, acc1 = {0.f, 0.f, 0.f, 0.f};
        {
            const int m   = n16;                 // A-operand row = lane&15
            const int rot = 8 * m;
#pragma unroll
            for (int kk = 0; kk < 32; kk += 2) {
                const int k0 = kk * 32 + q * 8;
                const f16x8 a0 = *(const f16x8*)&Alds[m * 1024 + ((k0      + rot) & 1023)];
                const f16x8 a1 = *(const f16x8*)&Alds[m * 1024 + ((k0 + 32 + rot) & 1023)];
                acc0 = __builtin_amdgcn_mfma_f32_16x16x32_f16(a0, Breg[kk],     acc0, 0, 0, 0);
                acc1 = __builtin_amdgcn_mfma_f32_16x16x32_f16(a1, Breg[kk + 1], acc1, 0, 0, 0);
            }
        }
        // C layout: col = lane&15, row = quad*4 + reg
#pragma unroll
        for (int r = 0; r < 4; ++r)
            glds[w][q * 4 + r][n16] = acc0[r] + acc1[r];
        __syncthreads();

        // ---- elementwise gates, state update, outputs --------------------------
        {
            const float yi = glds[0][eb][ej] + bi_i;
            const float yf = glds[1][eb][ej] + bi_f;
            const float yg = glds[2][eb][ej] + bi_g;
            const float yo = glds[3][eb][ej] + bi_o;
            cst = sigmoid_f(yf) * cst + sigmoid_f(yi) * tanh_f(yg);
            const float hn = sigmoid_f(yo) * tanh_f(cst);

            out[65536 + ((size_t)(gb0 + eb) * 1024 + t) * 512 + col0 + ej] = hn;
            if (t == 1023) {
                out[(size_t)(gb0 + eb) * 512 + col0 + ej]         = cst;  // cT
                out[32768 + (size_t)(gb0 + eb) * 512 + col0 + ej] = hn;   // hT
            }
            unsigned* dstu = (unsigned*)(exch + (size_t)((t + 1) & 1) * (64 * 512));
            __hip_atomic_store(&dstu[(gb0 + eb) * 512 + col0 + ej],
                               __float_as_uint(hn),
                               __ATOMIC_RELAXED, __HIP_MEMORY_SCOPE_AGENT);
        }
        __syncthreads();   // drains vmcnt: all h' stores device-visible before arrive

        if (t < 1023 && tid == 0) {
            __hip_atomic_fetch_add(bar, 1u, __ATOMIC_ACQ_REL, __HIP_MEMORY_SCOPE_AGENT);
        }
    }
}

extern "C" void kernel_launch(void* const* d_in, const int* in_sizes, int n_in,
                              void* d_out, int out_size, void* d_ws, size_t ws_size,
                              hipStream_t stream) {
    const float* x  = (const float*)d_in[0];
    const float* c0 = (const float*)d_in[1];
    const float* h0 = (const float*)d_in[2];
    const float* Wi = (const float*)d_in[3];
    const float* Wh = (const float*)d_in[4];
    const float* b  = (const float*)d_in[5];
    float* out = (float*)d_out;

    // ws layout: [0,1024) barrier counters (zeroed), then 2 x 64*512 f32 h-exchange
    hipMemsetAsync(d_ws, 0, 1024, stream);
    unsigned* bar = (unsigned*)d_ws;
    float* exch = (float*)((char*)d_ws + 1024);

    hipLaunchKernelGGL(lstm_persistent, dim3(128), dim3(256), 0, stream,
                       x, c0, h0, Wi, Wh, b, out, bar, exch);
}